// Round 7
// baseline (299.032 us; speedup 1.0000x reference)
//
#include <hip/hip_runtime.h>

#define BB 4
#define CIN 256
#define HW 35200            // 200*176
#define AA 6
#define NANCH (AA * HW)     // 211200
#define TOPK 100
#define NBIN 2048           // mapped score bins (8 KB LDS)
#define BINBASE 14208       // 0x37800000 >> 16
#define CAP 4096            // candidates per batch
#define SMAX 4096           // bitonic sort max size
#define TILES 138           // ceil(HW/256), 256 positions per block

// monotone (clamped) bin map for score bits, s in [0,1]
__device__ __forceinline__ unsigned sbin(unsigned bits) {
  int v = (int)(bits >> 16) - BINBASE;
  v = v < 0 ? 0 : v;
  v = v > (NBIN - 1) ? (NBIN - 1) : v;
  return (unsigned)v;
}

// ---------------- K1: cls head, channel-split 4 waves, P=4 stride-64 ----------------
// A<o>.{x,y,z,w} = partial logit o at positions lane+{0,64,128,192}.
#define DA(o) float4 A##o = make_float4(0.f, 0.f, 0.f, 0.f);
#define FMP(o, WS)                                          \
  A##o.x = fmaf(xv0, WS, A##o.x); A##o.y = fmaf(xv1, WS, A##o.y); \
  A##o.z = fmaf(xv2, WS, A##o.z); A##o.w = fmaf(xv3, WS, A##o.w);
#define REDS(o) { int ib = o * 256 + lane; red[ib] = A##o.x;        \
  red[ib + 64] = A##o.y; red[ib + 128] = A##o.z; red[ib + 192] = A##o.w; }
#define REDA(o) { int ib = o * 256 + lane; red[ib] += A##o.x;       \
  red[ib + 64] += A##o.y; red[ib + 128] += A##o.z; red[ib + 192] += A##o.w; }
#define RED_ALL(M) M(0) M(1) M(2) M(3) M(4) M(5) M(6) M(7) M(8) M(9) M(10) \
  M(11) M(12) M(13) M(14) M(15) M(16) M(17) M(18) M(19) M(20) M(21) M(22) M(23)

__global__ __launch_bounds__(256, 2) void k1_scores(
    const float* __restrict__ x, const float* __restrict__ cls_w,
    const float* __restrict__ cls_b, unsigned int* __restrict__ hist,
    float* __restrict__ maxsc) {
  int bid = blockIdx.x;
  int b = bid / TILES, tile = bid % TILES;
  int tid = threadIdx.x, wave = tid >> 6, lane = tid & 63;

  __shared__ __align__(16) float swf[CIN * 24];   // 24 KB, [c][o] transposed
  __shared__ float red[24 * 256];                 // 24 KB, [o][pos]
  __shared__ unsigned lh[NBIN];                   // 8 KB block histogram
  for (int i = tid; i < CIN * 24; i += 256)
    swf[(i & 255) * 24 + (i >> 8)] = cls_w[i];    // coalesced global read
  for (int i = tid; i < NBIN; i += 256) lh[i] = 0;
  __syncthreads();
  const float4* sw4 = (const float4*)swf;

  // 4 clamped position offsets (stride 64)
  int pbase = tile * 256 + lane;
  int o0 = pbase            < HW ? pbase       : HW - 1;
  int o1 = pbase + 64       < HW ? pbase + 64  : HW - 1;
  int o2 = pbase + 128      < HW ? pbase + 128 : HW - 1;
  int o3 = pbase + 192      < HW ? pbase + 192 : HW - 1;
  const float* xw = x + (size_t)b * CIN * HW + (size_t)(wave * 64) * HW;

  RED_ALL(DA)

#pragma unroll 4
  for (int c = 0; c < 64; ++c) {
    const float* xc = xw + (size_t)c * HW;
    float xv0 = xc[o0], xv1 = xc[o1], xv2 = xc[o2], xv3 = xc[o3];
    const float4* wr = sw4 + (wave * 64 + c) * 6;
    float4 w0 = wr[0], w1 = wr[1], w2 = wr[2];
    float4 w3 = wr[3], w4 = wr[4], w5 = wr[5];
    FMP(0, w0.x) FMP(1, w0.y) FMP(2, w0.z) FMP(3, w0.w)
    FMP(4, w1.x) FMP(5, w1.y) FMP(6, w1.z) FMP(7, w1.w)
    FMP(8, w2.x) FMP(9, w2.y) FMP(10, w2.z) FMP(11, w2.w)
    FMP(12, w3.x) FMP(13, w3.y) FMP(14, w3.z) FMP(15, w3.w)
    FMP(16, w4.x) FMP(17, w4.y) FMP(18, w4.z) FMP(19, w4.w)
    FMP(20, w5.x) FMP(21, w5.y) FMP(22, w5.z) FMP(23, w5.w)
  }

  // deterministic cross-wave reduction (conflict-free: consecutive lanes)
  if (wave == 0) { RED_ALL(REDS) }
  __syncthreads();
  if (wave == 1) { RED_ALL(REDA) }
  __syncthreads();
  if (wave == 2) { RED_ALL(REDA) }
  __syncthreads();
  if (wave == 3) { RED_ALL(REDA) }
  __syncthreads();

  // epilogue: one position per thread
  int hwg = tile * 256 + tid;
  if (hwg < HW) {
    float* mp = maxsc + (size_t)b * NANCH + (size_t)hwg * 6u;
#pragma unroll
    for (int a = 0; a < AA; ++a) {
      float l0 = red[(a * 4 + 0) * 256 + tid] + cls_b[a * 4 + 0];
      float l1 = red[(a * 4 + 1) * 256 + tid] + cls_b[a * 4 + 1];
      float l2 = red[(a * 4 + 2) * 256 + tid] + cls_b[a * 4 + 2];
      float l3 = red[(a * 4 + 3) * 256 + tid] + cls_b[a * 4 + 3];
      float m = fmaxf(fmaxf(l0, l1), fmaxf(l2, l3));
      float e0 = expf(l0 - m), e1 = expf(l1 - m);
      float e2 = expf(l2 - m), e3 = expf(l3 - m);
      float s = fmaxf(fmaxf(e1, e2), e3) / (e0 + e1 + e2 + e3);
      mp[a] = s;
      atomicAdd(&lh[sbin(__float_as_uint(s))], 1u);
    }
  }
  __syncthreads();
  unsigned* gh = hist + (size_t)b * NBIN;
  for (int i = tid; i < NBIN; i += 256) {
    unsigned c = lh[i];
    if (c) atomicAdd(&gh[i], c);
  }
}

// ---------------- K2: threshold bin per batch ----------------
__global__ __launch_bounds__(256) void k2_thresh(
    const unsigned int* __restrict__ hist, unsigned int* __restrict__ thresh) {
  int b = blockIdx.x, tid = threadIdx.x;
  const unsigned* h = hist + (size_t)b * NBIN;
  unsigned r[8];
  unsigned s = 0;
#pragma unroll
  for (int i = 0; i < 8; ++i) { r[i] = h[tid * 8 + i]; s += r[i]; }
  __shared__ unsigned seg[256];
  seg[tid] = s;
  __syncthreads();
  for (int d = 1; d < 256; d <<= 1) {   // inclusive suffix scan
    unsigned add = (tid + d < 256) ? seg[tid + d] : 0u;
    __syncthreads();
    seg[tid] += add;
    __syncthreads();
  }
  unsigned above = (tid < 255) ? seg[tid + 1] : 0u;
  if (above < TOPK && above + s >= TOPK) {   // exactly one thread
    unsigned c = above, T = 0;
    for (int i = 7; i >= 0; --i) {
      c += r[i];
      if (c >= TOPK) { T = tid * 8u + (unsigned)i; break; }
    }
    thresh[b] = T;
  }
}

// ---------------- K3: compact candidates (wave-aggregated atomics) ----------------
__global__ __launch_bounds__(256) void k3_compact(
    const float* __restrict__ maxsc, const unsigned int* __restrict__ thresh,
    unsigned int* __restrict__ cand_count, unsigned long long* __restrict__ cand) {
  unsigned p = blockIdx.x * 256u + threadIdx.x;   // [0, B*NANCH)
  unsigned b = p / NANCH, n = p % NANCH;          // b block-uniform
  unsigned bits = __float_as_uint(maxsc[p]);
  bool pred = sbin(bits) >= thresh[b];
  unsigned long long mask = __ballot(pred);
  if (mask) {
    int lane = threadIdx.x & 63;
    int leader = (int)__ffsll((unsigned long long)mask) - 1;
    unsigned base = 0;
    if (lane == leader)
      base = atomicAdd(&cand_count[b], (unsigned)__popcll(mask));
    base = __shfl(base, leader, 64);
    if (pred) {
      unsigned pos = base + (unsigned)__popcll(mask & ((1ull << lane) - 1ull));
      if (pos < CAP)
        cand[(size_t)b * CAP + pos] =
            ((unsigned long long)bits << 32) | (unsigned)(~n);
    }
  }
}

// ---------------- K4: bitonic sort candidates, emit topk ----------------
__global__ __launch_bounds__(256) void k4_sort(
    const unsigned long long* __restrict__ cand,
    const unsigned int* __restrict__ cand_count, unsigned int* __restrict__ topk) {
  int b = blockIdx.x, tid = threadIdx.x;
  __shared__ unsigned long long sh[SMAX];
  unsigned cnt = cand_count[b];
  if (cnt > CAP) cnt = CAP;
  unsigned S = 128;
  while (S < cnt) S <<= 1;
  for (unsigned t = tid; t < S; t += 256)
    sh[t] = (t < cnt) ? cand[(size_t)b * CAP + t] : 0ULL;
  __syncthreads();
  for (unsigned kk = 2; kk <= S; kk <<= 1) {
    for (unsigned jj = kk >> 1; jj > 0; jj >>= 1) {
      for (unsigned t = tid; t < S; t += 256) {
        unsigned ixj = t ^ jj;
        if (ixj > t) {
          unsigned long long a = sh[t], c = sh[ixj];
          bool sw = ((t & kk) == 0) ? (a < c) : (a > c);  // descending
          if (sw) { sh[t] = c; sh[ixj] = a; }
        }
      }
      __syncthreads();
    }
  }
  if (tid < TOPK)
    topk[b * TOPK + tid] = ~(unsigned)(sh[tid] & 0xFFFFFFFFULL);
}

// ---------------- K5: final heads + decode for selected anchors ----------------
__global__ __launch_bounds__(256) void k5_out(
    const float* __restrict__ x, const float* __restrict__ cls_w,
    const float* __restrict__ cls_b, const float* __restrict__ reg_w,
    const float* __restrict__ reg_b, const float* __restrict__ anchors,
    const unsigned int* __restrict__ topk, float* __restrict__ out) {
  int bk = blockIdx.x;            // [0, B*TOPK)
  int b = bk / TOPK, k = bk % TOPK;
  unsigned n = topk[b * TOPK + k];
  int a = (int)(n % AA);
  unsigned hw = n / AA;
  int tid = threadIdx.x;          // 256 == CIN

  float xv = x[(size_t)b * CIN * HW + (size_t)tid * HW + hw];
  float part[11];
#pragma unroll
  for (int j = 0; j < 4; ++j) part[j] = xv * cls_w[(a * 4 + j) * CIN + tid];
#pragma unroll
  for (int j = 0; j < 7; ++j) part[4 + j] = xv * reg_w[(a * 7 + j) * CIN + tid];

#pragma unroll
  for (int j = 0; j < 11; ++j) {
    float v = part[j];
    for (int off = 32; off > 0; off >>= 1) v += __shfl_down(v, off, 64);
    part[j] = v;
  }
  __shared__ float red[4][11];
  int wave = tid >> 6, lane = tid & 63;
  if (lane == 0) {
#pragma unroll
    for (int j = 0; j < 11; ++j) red[wave][j] = part[j];
  }
  __syncthreads();
  if (tid == 0) {
    float tot[11];
#pragma unroll
    for (int j = 0; j < 11; ++j)
      tot[j] = red[0][j] + red[1][j] + red[2][j] + red[3][j];
    float l0 = tot[0] + cls_b[a * 4 + 0];
    float l1 = tot[1] + cls_b[a * 4 + 1];
    float l2 = tot[2] + cls_b[a * 4 + 2];
    float l3 = tot[3] + cls_b[a * 4 + 3];
    float m = fmaxf(fmaxf(l0, l1), fmaxf(l2, l3));
    float e0 = expf(l0 - m), e1 = expf(l1 - m);
    float e2 = expf(l2 - m), e3 = expf(l3 - m);
    float inv = 1.0f / (e0 + e1 + e2 + e3);
    float* os = out + ((size_t)b * TOPK + k) * 4;
    os[0] = e0 * inv; os[1] = e1 * inv; os[2] = e2 * inv; os[3] = e3 * inv;
    const float* an = anchors + (size_t)n * 7;
    float xa = an[0], ya = an[1], za = an[2];
    float dxa = an[3], dya = an[4], dza = an[5], ra = an[6];
    float xt = tot[4] + reg_b[a * 7 + 0];
    float yt = tot[5] + reg_b[a * 7 + 1];
    float zt = tot[6] + reg_b[a * 7 + 2];
    float dxt = tot[7] + reg_b[a * 7 + 3];
    float dyt = tot[8] + reg_b[a * 7 + 4];
    float dzt = tot[9] + reg_b[a * 7 + 5];
    float rt = tot[10] + reg_b[a * 7 + 6];
    float diag = sqrtf(dxa * dxa + dya * dya);
    float* ob = out + (size_t)BB * TOPK * 4 + ((size_t)b * TOPK + k) * 7;
    ob[0] = xt * diag + xa;
    ob[1] = yt * diag + ya;
    ob[2] = zt * dza + za;
    ob[3] = expf(dxt) * dxa;
    ob[4] = expf(dyt) * dya;
    ob[5] = expf(dzt) * dza;
    ob[6] = rt + ra;
  }
}

extern "C" void kernel_launch(void* const* d_in, const int* in_sizes, int n_in,
                              void* d_out, int out_size, void* d_ws, size_t ws_size,
                              hipStream_t stream) {
  const float* x       = (const float*)d_in[0];
  const float* cls_w   = (const float*)d_in[1];
  const float* cls_b   = (const float*)d_in[2];
  const float* reg_w   = (const float*)d_in[3];
  const float* reg_b   = (const float*)d_in[4];
  const float* anchors = (const float*)d_in[5];
  float* out = (float*)d_out;

  // workspace layout (~3.6 MB)
  char* ws = (char*)d_ws;
  size_t off = 0;
  unsigned int* hist = (unsigned int*)(ws + off);        off += (size_t)BB * NBIN * 4; // 32 KB
  unsigned int* cand_count = (unsigned int*)(ws + off);  off += 64;
  unsigned int* thresh = (unsigned int*)(ws + off);      off += 64;
  unsigned long long* cand = (unsigned long long*)(ws + off); off += (size_t)BB * CAP * 8; // 128 KB
  unsigned int* topk = (unsigned int*)(ws + off);        off += 2048;
  float* maxsc = (float*)(ws + off);                     // 3.4 MB

  hipMemsetAsync(hist, 0, (size_t)BB * NBIN * 4 + 64, stream);  // hist + cand_count

  k1_scores<<<BB * TILES, 256, 0, stream>>>(x, cls_w, cls_b, hist, maxsc);
  k2_thresh<<<BB, 256, 0, stream>>>(hist, thresh);
  k3_compact<<<(BB * NANCH) / 256, 256, 0, stream>>>(maxsc, thresh, cand_count, cand);
  k4_sort<<<BB, 256, 0, stream>>>(cand, cand_count, topk);
  k5_out<<<BB * TOPK, 256, 0, stream>>>(x, cls_w, cls_b, reg_w, reg_b, anchors,
                                        topk, out);
}